// Round 5
// baseline (675.688 us; speedup 1.0000x reference)
//
#include <hip/hip_runtime.h>

#define B_ 16
#define C_ 192
#define T_ 2048
#define F_ 256
#define HALF_ 96

typedef short s16x8 __attribute__((ext_vector_type(8)));
typedef float f32x4 __attribute__((ext_vector_type(4)));
typedef unsigned short ushort;

union U8 { uint4 v; ushort u[8]; };
union U4 { uint2 v; ushort u[4]; };

__device__ __forceinline__ float gelu_f(float x) {
  return 0.5f * x * (1.f + erff(x * 0.70710678118654752f));
}
__device__ __forceinline__ ushort f2bf(float f) {
  unsigned u = __float_as_uint(f);
  unsigned r = u + 0x7fff + ((u >> 16) & 1);
  return (ushort)(r >> 16);
}
__device__ __forceinline__ float bf2f(ushort h) {
  return __uint_as_float(((unsigned)h) << 16);
}

// ---------------------------------------------------------------------------
// K-wcvt: fp32 -> bf16 (single)
// ---------------------------------------------------------------------------
__global__ void wcvt_k(const float* __restrict__ w, ushort* __restrict__ wb,
                       int n) {
  int i = blockIdx.x * 256 + threadIdx.x;
  if (i < n) wb[i] = f2bf(w[i]);
}

// ---------------------------------------------------------------------------
// K1: hT[b][t][f] = pre_w[f,:] @ x0[b,:,t] + pre_b[f]   (bf16, [t][c] layout)
// grid (T/256, F/8, B); thread = one t, 8 consecutive f (uniform per wave)
// ---------------------------------------------------------------------------
__global__ void pre_gemm_k(const float* __restrict__ x,
                           const float* __restrict__ pw,
                           const float* __restrict__ pb,
                           ushort* __restrict__ hT) {
  int t = blockIdx.x * 256 + threadIdx.x;
  int f0 = blockIdx.y * 8;
  int b = blockIdx.z;
  float acc[8];
#pragma unroll
  for (int j = 0; j < 8; ++j) acc[j] = pb[f0 + j];
  const float* xp = x + ((size_t)b * C_) * T_ + t;
  const float* wp = pw + (size_t)f0 * HALF_;
#pragma unroll 4
  for (int c = 0; c < HALF_; ++c) {
    float xv = xp[(size_t)c * T_];
#pragma unroll
    for (int j = 0; j < 8; ++j)
      acc[j] = fmaf(wp[j * HALF_ + c], xv, acc[j]);
  }
  U8 pk;
#pragma unroll
  for (int j = 0; j < 8; ++j) pk.u[j] = f2bf(acc[j]);
  *(uint4*)(hT + ((size_t)b * T_ + t) * F_ + f0) = pk.v;
}

// ---------------------------------------------------------------------------
// K2a: depthwise conv + channel-norm + gelu.  hT [b][t][c] -> y1T [b][t][c]
// grid (T/64, B), block 256. thread = (t = tid&63, 64 channels cg*64..)
// ---------------------------------------------------------------------------
__global__ __launch_bounds__(256, 4) void conv_k(
    const ushort* __restrict__ hT, ushort* __restrict__ y1T,
    const float* __restrict__ mask,
    const float* __restrict__ dww, const float* __restrict__ dwb,
    const float* __restrict__ g1, const float* __restrict__ b1,
    int dil) {
  __shared__ ushort y1b[64 * 264];
  __shared__ float scratch[512];
  __shared__ float stat[128];
  int tid = threadIdx.x;
  int b = blockIdx.y;
  int t0 = blockIdx.x * 64;
  int t = tid & 63, cg = tid >> 6;
  int tz = t0 + t;
  int tm = tz - dil, tp = tz + dil;
  bool vm = (tm >= 0), vp = (tp < T_);
  float mm = vm ? mask[b * T_ + tm] : 0.f;
  float mz = mask[b * T_ + tz];
  float mp = vp ? mask[b * T_ + tp] : 0.f;
  const ushort* hb = hT + (size_t)b * T_ * F_;
  uint4 zero4 = make_uint4(0, 0, 0, 0);
  float s = 0.f, q = 0.f;
#pragma unroll 1
  for (int g = 0; g < 8; ++g) {
    int c = cg * 64 + g * 8;
    U8 r0, r1, r2, pk;
    r0.v = vm ? *(const uint4*)(hb + (size_t)tm * F_ + c) : zero4;
    r1.v = *(const uint4*)(hb + (size_t)tz * F_ + c);
    r2.v = vp ? *(const uint4*)(hb + (size_t)tp * F_ + c) : zero4;
#pragma unroll
    for (int i = 0; i < 8; ++i) {
      int ci = c + i;
      float v = fmaf(dww[ci * 3], bf2f(r0.u[i]) * mm,
                fmaf(dww[ci * 3 + 1], bf2f(r1.u[i]) * mz,
                fmaf(dww[ci * 3 + 2], bf2f(r2.u[i]) * mp, dwb[ci])));
      pk.u[i] = f2bf(v);
      s += v;
      q = fmaf(v, v, q);
    }
    *(uint4*)&y1b[t * 264 + c] = pk.v;
  }
  scratch[cg * 64 + t] = s;
  scratch[256 + cg * 64 + t] = q;
  __syncthreads();
  if (tid < 64) {
    float ss = scratch[tid] + scratch[64 + tid] + scratch[128 + tid] + scratch[192 + tid];
    float qq = scratch[256 + tid] + scratch[320 + tid] + scratch[384 + tid] + scratch[448 + tid];
    float mean = ss * (1.f / 256.f);
    float var = qq * (1.f / 256.f) - mean * mean;
    stat[tid] = mean;
    stat[64 + tid] = rsqrtf(var + 1e-5f);
  }
  __syncthreads();
  float mean = stat[t], rstd = stat[64 + t];
#pragma unroll 1
  for (int g = 0; g < 8; ++g) {
    int c = cg * 64 + g * 8;
    U8 pk;
    pk.v = *(const uint4*)&y1b[t * 264 + c];
#pragma unroll
    for (int i = 0; i < 8; ++i) {
      float v = (bf2f(pk.u[i]) - mean) * rstd * g1[c + i] + b1[c + i];
      pk.u[i] = f2bf(gelu_f(v));
    }
    *(uint4*)(y1T + ((size_t)b * T_ + tz) * F_ + c) = pk.v;
  }
}

// ---------------------------------------------------------------------------
// K2b: pointwise MFMA GEMM (bf16 x bf16) + cnorm + gelu + residual
// y1T [b][t][c], hT_in [b][t][c] -> hT_out [b][t][c] (optionally * mask)
// grid (T/64, B), block 256 = 4 waves x (4mt x 4nt); M=256, N=64, K=256
// ---------------------------------------------------------------------------
template <bool MASK_OUT>
__global__ __launch_bounds__(256, 4) void pw_gemm_k(
    const ushort* __restrict__ y1T, const ushort* __restrict__ hT_in,
    ushort* __restrict__ hT_out, const float* __restrict__ mask,
    const ushort* __restrict__ pw, const float* __restrict__ pwb,
    const float* __restrict__ g2, const float* __restrict__ b2) {
  __shared__ __align__(16) ushort bsm[64 * 264];
  __shared__ float stat[128];
  float* scratch = (float*)bsm;  // overlay after GEMM (8 KB of 33.8)
  int tid = threadIdx.x;
  int b = blockIdx.y;
  int t0 = blockIdx.x * 64;
  int lane = tid & 63, wid = tid >> 6, col = lane & 15, quad = lane >> 4;

#pragma unroll
  for (int p = 0; p < 8; ++p) {
    int idx = tid + p * 256;
    int row = idx >> 5;
    int u = idx & 31;
    *(uint4*)(bsm + row * 264 + u * 8) =
        *(const uint4*)(y1T + ((size_t)b * T_ + t0 + row) * F_ + u * 8);
  }
  f32x4 acc[4][4];
#pragma unroll
  for (int mt = 0; mt < 4; ++mt)
#pragma unroll
    for (int nt = 0; nt < 4; ++nt) acc[mt][nt] = (f32x4)(0.f);
  __syncthreads();
#pragma unroll 1
  for (int ks = 0; ks < 8; ++ks) {
    int kloc = ks * 32 + quad * 8;
    s16x8 av[4];
#pragma unroll
    for (int mt = 0; mt < 4; ++mt)
      av[mt] = *(const s16x8*)(pw + (size_t)((wid * 4 + mt) * 16 + col) * F_ + kloc);
#pragma unroll
    for (int nt = 0; nt < 4; ++nt) {
      s16x8 bv = *(const s16x8*)(bsm + (nt * 16 + col) * 264 + kloc);
#pragma unroll
      for (int mt = 0; mt < 4; ++mt)
        acc[mt][nt] = __builtin_amdgcn_mfma_f32_16x16x32_bf16(av[mt], bv, acc[mt][nt], 0, 0, 0);
    }
  }
  __syncthreads();
  // bias + per-t partial stats (overlay into bsm)
  float pwbv[4][4];
#pragma unroll
  for (int mt = 0; mt < 4; ++mt)
#pragma unroll
    for (int r = 0; r < 4; ++r)
      pwbv[mt][r] = pwb[(wid * 4 + mt) * 16 + quad * 4 + r];
#pragma unroll
  for (int nt = 0; nt < 4; ++nt) {
    float s = 0.f, q = 0.f;
#pragma unroll
    for (int mt = 0; mt < 4; ++mt)
#pragma unroll
      for (int r = 0; r < 4; ++r) {
        float v = acc[mt][nt][r] + pwbv[mt][r];
        acc[mt][nt][r] = v;
        s += v;
        q = fmaf(v, v, q);
      }
    int pcol = (wid * 4 + quad) * 64 + nt * 16 + col;
    scratch[pcol] = s;
    scratch[1024 + pcol] = q;
  }
  __syncthreads();
  if (tid < 64) {
    float s = 0.f, q = 0.f;
#pragma unroll
    for (int p = 0; p < 16; ++p) {
      s += scratch[p * 64 + tid];
      q += scratch[1024 + p * 64 + tid];
    }
    float mean = s * (1.f / 256.f);
    float var = q * (1.f / 256.f) - mean * mean;
    stat[tid] = mean;
    stat[64 + tid] = rsqrtf(var + 1e-5f);
  }
  __syncthreads();
  float g2v[4][4], b2v[4][4];
#pragma unroll
  for (int mt = 0; mt < 4; ++mt)
#pragma unroll
    for (int r = 0; r < 4; ++r) {
      int o = (wid * 4 + mt) * 16 + quad * 4 + r;
      g2v[mt][r] = g2[o];
      b2v[mt][r] = b2[o];
    }
#pragma unroll
  for (int nt = 0; nt < 4; ++nt) {
    int t = t0 + nt * 16 + col;
    float mean = stat[nt * 16 + col], rstd = stat[64 + nt * 16 + col];
    float mval = MASK_OUT ? mask[(size_t)b * T_ + t] : 1.f;
#pragma unroll
    for (int mt = 0; mt < 4; ++mt) {
      int o = (wid * 4 + mt) * 16 + quad * 4;
      U4 rv, wv;
      rv.v = *(const uint2*)(hT_in + ((size_t)b * T_ + t) * F_ + o);
#pragma unroll
      for (int r = 0; r < 4; ++r) {
        float u = (acc[mt][nt][r] - mean) * rstd * g2v[mt][r] + b2v[mt][r];
        float hv = bf2f(rv.u[r]) + gelu_f(u);
        wv.u[r] = f2bf(MASK_OUT ? hv * mval : hv);
      }
      *(uint2*)(hT_out + ((size_t)b * T_ + t) * F_ + o) = wv.v;
    }
  }
}

// ---------------------------------------------------------------------------
// K3: proj GEMM (single-bf16) + RQ spline + logdet
// grid (T/64, 12, B); block 256. M=232(pad256), N=64, K=256 staged once.
// ---------------------------------------------------------------------------
__global__ __launch_bounds__(256, 4) void proj_spline_k(
    const ushort* __restrict__ hT,
    const float* __restrict__ x, const float* __restrict__ mask,
    const ushort* __restrict__ w_bf, const float* __restrict__ pb,
    float* __restrict__ out, float* __restrict__ logdet) {
  __shared__ __align__(16) ushort bsm[64 * 264];
  __shared__ float red[4];
  ushort* s_lds = bsm;  // s-tile [232][68] bf16 overlay

  int tid = threadIdx.x;
  int t0 = blockIdx.x * 64;
  int chunk = blockIdx.y;
  int b = blockIdx.z;
  int lane = tid & 63, wid = tid >> 6, col = lane & 15, quad = lane >> 4;

#pragma unroll
  for (int p = 0; p < 8; ++p) {
    int idx = tid + p * 256;
    int row = idx >> 5;
    int u = idx & 31;
    *(uint4*)(bsm + row * 264 + u * 8) =
        *(const uint4*)(hT + ((size_t)b * T_ + t0 + row) * F_ + u * 8);
  }
  f32x4 acc[4][4];
#pragma unroll
  for (int mt = 0; mt < 4; ++mt)
#pragma unroll
    for (int nt = 0; nt < 4; ++nt) acc[mt][nt] = (f32x4)(0.f);
  int rowA[4];
#pragma unroll
  for (int mt = 0; mt < 4; ++mt) {
    int r = chunk * 232 + (wid * 4 + mt) * 16 + col;
    rowA[mt] = r > 2783 ? 2783 : r;
  }
  __syncthreads();
#pragma unroll 1
  for (int ks = 0; ks < 8; ++ks) {
    int kloc = ks * 32 + quad * 8;
    s16x8 av[4];
#pragma unroll
    for (int mt = 0; mt < 4; ++mt)
      av[mt] = *(const s16x8*)(w_bf + (size_t)rowA[mt] * F_ + kloc);
#pragma unroll
    for (int nt = 0; nt < 4; ++nt) {
      s16x8 bv = *(const s16x8*)(bsm + (nt * 16 + col) * 264 + kloc);
#pragma unroll
      for (int mt = 0; mt < 4; ++mt)
        acc[mt][nt] = __builtin_amdgcn_mfma_f32_16x16x32_bf16(av[mt], bv, acc[mt][nt], 0, 0, 0);
    }
  }
  __syncthreads();
  {
    float mv[4];
#pragma unroll
    for (int nt = 0; nt < 4; ++nt)
      mv[nt] = mask[(size_t)b * T_ + t0 + nt * 16 + col];
#pragma unroll
    for (int mt = 0; mt < 4; ++mt) {
#pragma unroll
      for (int r = 0; r < 4; ++r) {
        int local = (wid * 4 + mt) * 16 + quad * 4 + r;
        if (local < 232) {
          float bias = pb[chunk * 232 + local];
#pragma unroll
          for (int nt = 0; nt < 4; ++nt)
            s_lds[local * 68 + nt * 16 + col] =
                f2bf((acc[mt][nt][r] + bias) * mv[nt]);
        }
      }
    }
  }
  __syncthreads();
  // ---- spline: 8 ch x 64 t per block; 2 elements per thread ----
  float lad_sum = 0.f;
  int ch_i = tid >> 5, ti = tid & 31;
  int ch = chunk * 8 + ch_i;
#pragma unroll 1
  for (int pass = 0; pass < 2; ++pass) {
    int t = ti + pass * 32;
    float s[29];
#pragma unroll
    for (int j = 0; j < 29; ++j) s[j] = bf2f(s_lds[(ch_i * 29 + j) * 68 + t]);
    float xin = x[((size_t)b * C_ + HALF_ + ch) * T_ + t0 + t];
    float mval = mask[(size_t)b * T_ + t0 + t];
    // widths (no max-subtract: |s*0.0625| is small)
    float ew[10];
    float esum = 0.f;
#pragma unroll
    for (int j = 0; j < 10; ++j) { ew[j] = __expf(s[j] * 0.0625f); esum += ew[j]; }
    float inv = 1.f / esum;
    float cw[11];
    cw[0] = -5.f;
    float csum = 0.f;
#pragma unroll
    for (int j = 0; j < 9; ++j) {
      csum += fmaf(0.99f, ew[j] * inv, 0.001f);
      cw[j + 1] = fmaf(10.f, csum, -5.f);
    }
    cw[10] = 5.f;
    float eh[10];
    esum = 0.f;
#pragma unroll
    for (int j = 0; j < 10; ++j) { eh[j] = __expf(s[10 + j] * 0.0625f); esum += eh[j]; }
    inv = 1.f / esum;
    float chh[11];
    chh[0] = -5.f;
    csum = 0.f;
#pragma unroll
    for (int j = 0; j < 9; ++j) {
      csum += fmaf(0.99f, eh[j] * inv, 0.001f);
      chh[j + 1] = fmaf(10.f, csum, -5.f);
    }
    chh[10] = 5.f;
    float dv[11];
    dv[0] = 1.f; dv[10] = 1.f;
#pragma unroll
    for (int j = 1; j < 10; ++j) {
      float u = s[19 + j];
      float sp = (u > 15.f) ? u : __logf(1.f + __expf(u));
      dv[j] = 0.001f + sp;
    }
    float xc = fminf(fmaxf(xin, -5.f), 5.f);
    bool inside = (xin >= -5.f) && (xin <= 5.f);
    int idx = 0;
#pragma unroll
    for (int k = 1; k <= 10; ++k) idx += (xc >= cw[k]) ? 1 : 0;
    idx = idx > 9 ? 9 : idx;
    float in_cw = cw[0], in_w = cw[1] - cw[0];
    float in_ch = chh[0], in_h = chh[1] - chh[0];
    float d0 = dv[0], d1 = dv[1];
#pragma unroll
    for (int k = 1; k < 10; ++k) {
      bool sel = (idx == k);
      in_cw = sel ? cw[k] : in_cw;
      in_w = sel ? (cw[k + 1] - cw[k]) : in_w;
      in_ch = sel ? chh[k] : in_ch;
      in_h = sel ? (chh[k + 1] - chh[k]) : in_h;
      d0 = sel ? dv[k] : d0;
      d1 = sel ? dv[k + 1] : d1;
    }
    float theta = (xc - in_cw) / in_w;
    float delta = in_h / in_w;
    float omt = 1.f - theta;
    float t1m = theta * omt;
    float th2 = theta * theta;
    float denom = delta + (d0 + d1 - 2.f * delta) * t1m;
    float num = in_h * (delta * th2 + d0 * t1m);
    float outv = in_ch + num / denom;
    float dnum = delta * delta * (d1 * th2 + 2.f * delta * t1m + d0 * omt * omt);
    float lad = __logf(dnum) - 2.f * __logf(denom);
    float res = inside ? outv : xin;
    float ladv = inside ? lad : 0.f;
    out[((size_t)b * C_ + HALF_ + ch) * T_ + t0 + t] = res * mval;
    lad_sum += ladv * mval;
  }
#pragma unroll
  for (int off = 32; off > 0; off >>= 1)
    lad_sum += __shfl_down(lad_sum, off, 64);
  if ((tid & 63) == 0) red[tid >> 6] = lad_sum;
  __syncthreads();
  if (tid == 0)
    atomicAdd(logdet + b, red[0] + red[1] + red[2] + red[3]);
}

// ---------------------------------------------------------------------------
// K4: out[:, :96, :] = x0 * mask
// ---------------------------------------------------------------------------
__global__ void copy_x0_k(const float* __restrict__ x,
                          const float* __restrict__ mask,
                          float* __restrict__ out) {
  int i = blockIdx.x * 256 + threadIdx.x;
  int b = i / (HALF_ * T_ / 4);
  int r = i - b * (HALF_ * T_ / 4);
  int t4 = r & (T_ / 4 - 1);
  float4 v = ((const float4*)(x + (size_t)b * C_ * T_))[r];
  float4 m = ((const float4*)(mask + (size_t)b * T_))[t4];
  v.x *= m.x; v.y *= m.y; v.z *= m.z; v.w *= m.w;
  ((float4*)(out + (size_t)b * C_ * T_))[r] = v;
}

extern "C" void kernel_launch(void* const* d_in, const int* in_sizes, int n_in,
                              void* d_out, int out_size, void* d_ws, size_t ws_size,
                              hipStream_t stream) {
  const float* x      = (const float*)d_in[0];
  const float* mask   = (const float*)d_in[1];
  const float* pre_w  = (const float*)d_in[2];
  const float* pre_b  = (const float*)d_in[3];
  const float* dw_w   = (const float*)d_in[4];
  const float* dw_b   = (const float*)d_in[5];
  const float* pw_w   = (const float*)d_in[6];
  const float* pw_b   = (const float*)d_in[7];
  const float* g1     = (const float*)d_in[8];
  const float* b1     = (const float*)d_in[9];
  const float* g2     = (const float*)d_in[10];
  const float* b2     = (const float*)d_in[11];
  const float* proj_w = (const float*)d_in[12];
  const float* proj_b = (const float*)d_in[13];
  float* out = (float*)d_out;
  float* logdet = out + (size_t)B_ * C_ * T_;

  const size_t HSZ = (size_t)B_ * T_ * F_;   // 8.39M elems = 16.78 MB bf16
  ushort* hA   = (ushort*)d_ws;
  ushort* hB   = hA + HSZ;
  ushort* y1   = hB + HSZ;
  ushort* wprj = y1 + HSZ;                   // 2784*256
  ushort* wpw  = wprj + 2784 * 256;          // 3*256*256

  hipMemsetAsync(logdet, 0, B_ * sizeof(float), stream);
  wcvt_k<<<dim3((2784 * 256 + 255) / 256), 256, 0, stream>>>(proj_w, wprj, 2784 * 256);
  wcvt_k<<<dim3((3 * F_ * F_ + 255) / 256), 256, 0, stream>>>(pw_w, wpw, 3 * F_ * F_);
  pre_gemm_k<<<dim3(T_ / 256, F_ / 8, B_), 256, 0, stream>>>(x, pre_w, pre_b, hA);

  // layer 0
  conv_k<<<dim3(T_ / 64, B_), 256, 0, stream>>>(hA, y1, mask, dw_w, dw_b, g1, b1, 1);
  pw_gemm_k<false><<<dim3(T_ / 64, B_), 256, 0, stream>>>(y1, hA, hB, mask,
      wpw, pw_b, g2, b2);
  // layer 1
  conv_k<<<dim3(T_ / 64, B_), 256, 0, stream>>>(hB, y1, mask,
      dw_w + F_ * 3, dw_b + F_, g1 + F_, b1 + F_, 3);
  pw_gemm_k<false><<<dim3(T_ / 64, B_), 256, 0, stream>>>(y1, hB, hA, mask,
      wpw + F_ * F_, pw_b + F_, g2 + F_, b2 + F_);
  // layer 2 (masked output for proj)
  conv_k<<<dim3(T_ / 64, B_), 256, 0, stream>>>(hA, y1, mask,
      dw_w + 2 * F_ * 3, dw_b + 2 * F_, g1 + 2 * F_, b1 + 2 * F_, 9);
  pw_gemm_k<true><<<dim3(T_ / 64, B_), 256, 0, stream>>>(y1, hA, hB, mask,
      wpw + 2 * F_ * F_, pw_b + 2 * F_, g2 + 2 * F_, b2 + 2 * F_);

  copy_x0_k<<<dim3(B_ * HALF_ * T_ / 4 / 256), 256, 0, stream>>>(x, mask, out);
  proj_spline_k<<<dim3(T_ / 64, 12, B_), 256, 0, stream>>>(hB, x, mask,
      wprj, proj_b, out, logdet);
}

// Round 6
// 414.766 us; speedup vs baseline: 1.6291x; 1.6291x over previous
//
#include <hip/hip_runtime.h>

#define B_ 16
#define C_ 192
#define T_ 2048
#define F_ 256
#define HALF_ 96

typedef short s16x8 __attribute__((ext_vector_type(8)));
typedef float f32x4 __attribute__((ext_vector_type(4)));
typedef unsigned short ushort;

union U8 { uint4 v; ushort u[8]; };
union U4 { uint2 v; ushort u[4]; };

__device__ __forceinline__ float gelu_f(float x) {
  return 0.5f * x * (1.f + erff(x * 0.70710678118654752f));
}
__device__ __forceinline__ ushort f2bf(float f) {
  unsigned u = __float_as_uint(f);
  unsigned r = u + 0x7fff + ((u >> 16) & 1);
  return (ushort)(r >> 16);
}
__device__ __forceinline__ float bf2f(ushort h) {
  return __uint_as_float(((unsigned)h) << 16);
}

// ---------------------------------------------------------------------------
// K-wcvt: fp32 -> bf16
// ---------------------------------------------------------------------------
__global__ void wcvt_k(const float* __restrict__ w, ushort* __restrict__ wb,
                       int n) {
  int i = blockIdx.x * 256 + threadIdx.x;
  if (i < n) wb[i] = f2bf(w[i]);
}

// ---------------------------------------------------------------------------
// K1: pre GEMM via MFMA.  x0 fp32 [c][t] -> staged bf16 LDS [t][96] ->
// hT[b][t][f] = pre_w @ x0 + pre_b   (bf16 [t][c], coalesced store via LDS)
// grid (T/64, B), block 256.
// ---------------------------------------------------------------------------
__global__ __launch_bounds__(256, 3) void pre_k(
    const float* __restrict__ x, const ushort* __restrict__ wb,  // [256][96]
    const float* __restrict__ pb, ushort* __restrict__ hT) {
  __shared__ ushort xb[64 * 104];                 // [t][96 pad->104]
  __shared__ __align__(16) ushort ob[64 * 264];   // out staging [t][c]
  int tid = threadIdx.x;
  int b = blockIdx.y;
  int t0 = blockIdx.x * 64;
  // stage x0 (coalesced fp32 reads, lanes over t), bf16 scatter to LDS
#pragma unroll
  for (int p = 0; p < 24; ++p) {
    int idx = tid + p * 256;          // 96*64 = 6144
    int c = idx >> 6, t = idx & 63;
    xb[t * 104 + c] = f2bf(x[((size_t)b * C_ + c) * T_ + t0 + t]);
  }
  __syncthreads();
  int lane = tid & 63, wid = tid >> 6, col = lane & 15, quad = lane >> 4;
  f32x4 acc[4][4];
#pragma unroll
  for (int mt = 0; mt < 4; ++mt)
#pragma unroll
    for (int nt = 0; nt < 4; ++nt) acc[mt][nt] = (f32x4)(0.f);
#pragma unroll
  for (int ks = 0; ks < 3; ++ks) {
    int kloc = ks * 32 + quad * 8;
    s16x8 av[4];
#pragma unroll
    for (int mt = 0; mt < 4; ++mt)
      av[mt] = *(const s16x8*)(wb + (size_t)((wid * 4 + mt) * 16 + col) * 96 + kloc);
#pragma unroll
    for (int nt = 0; nt < 4; ++nt) {
      s16x8 bv = *(const s16x8*)(xb + (nt * 16 + col) * 104 + kloc);
#pragma unroll
      for (int mt = 0; mt < 4; ++mt)
        acc[mt][nt] = __builtin_amdgcn_mfma_f32_16x16x32_bf16(av[mt], bv, acc[mt][nt], 0, 0, 0);
    }
  }
  float pbv[4][4];
#pragma unroll
  for (int mt = 0; mt < 4; ++mt)
#pragma unroll
    for (int r = 0; r < 4; ++r)
      pbv[mt][r] = pb[(wid * 4 + mt) * 16 + quad * 4 + r];
#pragma unroll
  for (int nt = 0; nt < 4; ++nt) {
    int t = nt * 16 + col;
#pragma unroll
    for (int mt = 0; mt < 4; ++mt) {
      int o = (wid * 4 + mt) * 16 + quad * 4;
      U4 wv;
#pragma unroll
      for (int r = 0; r < 4; ++r) wv.u[r] = f2bf(acc[mt][nt][r] + pbv[mt][r]);
      *(uint2*)&ob[t * 264 + o] = wv.v;
    }
  }
  __syncthreads();
#pragma unroll
  for (int p = 0; p < 8; ++p) {
    int idx = tid + p * 256;
    int trow = idx >> 5, cc = (idx & 31) * 8;
    *(uint4*)(hT + ((size_t)b * T_ + t0 + trow) * F_ + cc) =
        *(const uint4*)&ob[trow * 264 + cc];
  }
}

// ---------------------------------------------------------------------------
// K2: fused layer: conv+cnorm+gelu (lanes-over-channels, shfl stats) ->
//     LDS y1 [t][c] -> MFMA pw GEMM -> cnorm+gelu+residual -> coalesced out.
// grid (T/64, B), block 256.
// ---------------------------------------------------------------------------
template <bool MASK_OUT>
__global__ __launch_bounds__(256, 4) void layer_k(
    const ushort* __restrict__ hT_in, ushort* __restrict__ hT_out,
    const float* __restrict__ mask,
    const float* __restrict__ dww, const float* __restrict__ dwb,
    const float* __restrict__ g1, const float* __restrict__ b1,
    const ushort* __restrict__ pw, const float* __restrict__ pwb,
    const float* __restrict__ g2, const float* __restrict__ b2,
    int dil) {
  __shared__ __align__(16) ushort y1b[64 * 264];  // [t][c] bf16 (33.8 KB)
  __shared__ float stat[128];
  float* scratch = (float*)y1b;  // overlay (post-GEMM only)
  int tid = threadIdx.x;
  int b = blockIdx.y;
  int t0 = blockIdx.x * 64;
  const ushort* hb = hT_in + (size_t)b * T_ * F_;
  const float* mrow = mask + (size_t)b * T_;

  // ---- Phase A: conv + norm1 + gelu, one t per 32-lane half-wave ----
  {
    int lane32 = tid & 31;
    int half = tid >> 5;          // 0..7
    int c0 = lane32 * 8;
    float dw0[8], dw1[8], dw2[8], dbv[8], g1v[8], b1v[8];
#pragma unroll
    for (int i = 0; i < 8; ++i) {
      int c = c0 + i;
      dw0[i] = dww[c * 3];
      dw1[i] = dww[c * 3 + 1];
      dw2[i] = dww[c * 3 + 2];
      dbv[i] = dwb[c];
      g1v[i] = g1[c];
      b1v[i] = b1[c];
    }
    uint4 zero4 = make_uint4(0, 0, 0, 0);
#pragma unroll 1
    for (int pass = 0; pass < 8; ++pass) {
      int t = pass * 8 + half;
      int tz = t0 + t, tm = tz - dil, tp = tz + dil;
      bool vm = (tm >= 0), vp = (tp < T_);
      float mm = vm ? mrow[tm] : 0.f;
      float mz = mrow[tz];
      float mp = vp ? mrow[tp] : 0.f;
      U8 r0, r1, r2;
      r0.v = vm ? *(const uint4*)(hb + (size_t)tm * F_ + c0) : zero4;
      r1.v = *(const uint4*)(hb + (size_t)tz * F_ + c0);
      r2.v = vp ? *(const uint4*)(hb + (size_t)tp * F_ + c0) : zero4;
      float v[8];
      float s = 0.f, q = 0.f;
#pragma unroll
      for (int i = 0; i < 8; ++i) {
        float vv = fmaf(dw0[i], bf2f(r0.u[i]) * mm,
                   fmaf(dw1[i], bf2f(r1.u[i]) * mz,
                   fmaf(dw2[i], bf2f(r2.u[i]) * mp, dbv[i])));
        v[i] = vv;
        s += vv;
        q = fmaf(vv, vv, q);
      }
#pragma unroll
      for (int m = 1; m < 32; m <<= 1) {
        s += __shfl_xor(s, m, 32);
        q += __shfl_xor(q, m, 32);
      }
      float mean = s * (1.f / 256.f);
      float var = q * (1.f / 256.f) - mean * mean;
      float rstd = rsqrtf(var + 1e-5f);
      U8 pk;
#pragma unroll
      for (int i = 0; i < 8; ++i) {
        float u = (v[i] - mean) * rstd * g1v[i] + b1v[i];
        pk.u[i] = f2bf(gelu_f(u));
      }
      *(uint4*)&y1b[t * 264 + c0] = pk.v;
    }
  }
  __syncthreads();
  // ---- Phase B: MFMA GEMM  W(256x256) @ y1(256k x 64t) ----
  int lane = tid & 63, wid = tid >> 6, col = lane & 15, quad = lane >> 4;
  f32x4 acc[4][4];
#pragma unroll
  for (int mt = 0; mt < 4; ++mt)
#pragma unroll
    for (int nt = 0; nt < 4; ++nt) acc[mt][nt] = (f32x4)(0.f);
#pragma unroll 1
  for (int ks = 0; ks < 8; ++ks) {
    int kloc = ks * 32 + quad * 8;
    s16x8 av[4];
#pragma unroll
    for (int mt = 0; mt < 4; ++mt)
      av[mt] = *(const s16x8*)(pw + (size_t)((wid * 4 + mt) * 16 + col) * F_ + kloc);
#pragma unroll
    for (int nt = 0; nt < 4; ++nt) {
      s16x8 bv = *(const s16x8*)(y1b + (nt * 16 + col) * 264 + kloc);
#pragma unroll
      for (int mt = 0; mt < 4; ++mt)
        acc[mt][nt] = __builtin_amdgcn_mfma_f32_16x16x32_bf16(av[mt], bv, acc[mt][nt], 0, 0, 0);
    }
  }
  __syncthreads();  // y1b reads done -> scratch overlay safe
  // ---- Phase C: bias + per-t stats (partials in scratch) ----
  float pwbv[4][4];
#pragma unroll
  for (int mt = 0; mt < 4; ++mt)
#pragma unroll
    for (int r = 0; r < 4; ++r)
      pwbv[mt][r] = pwb[(wid * 4 + mt) * 16 + quad * 4 + r];
#pragma unroll
  for (int nt = 0; nt < 4; ++nt) {
    float s = 0.f, q = 0.f;
#pragma unroll
    for (int mt = 0; mt < 4; ++mt)
#pragma unroll
      for (int r = 0; r < 4; ++r) {
        float v = acc[mt][nt][r] + pwbv[mt][r];
        acc[mt][nt][r] = v;
        s += v;
        q = fmaf(v, v, q);
      }
    int pcol = (wid * 4 + quad) * 64 + nt * 16 + col;
    scratch[pcol] = s;
    scratch[1024 + pcol] = q;
  }
  __syncthreads();
  if (tid < 64) {
    float s = 0.f, q = 0.f;
#pragma unroll
    for (int p = 0; p < 16; ++p) {
      s += scratch[p * 64 + tid];
      q += scratch[1024 + p * 64 + tid];
    }
    float mean = s * (1.f / 256.f);
    float var = q * (1.f / 256.f) - mean * mean;
    stat[tid] = mean;
    stat[64 + tid] = rsqrtf(var + 1e-5f);
  }
  __syncthreads();
  // ---- Phase D: norm2 + gelu -> y1b bf16 [t][c] (clobbers scratch, ok) ----
  {
    float g2v[4][4], b2v[4][4];
#pragma unroll
    for (int mt = 0; mt < 4; ++mt)
#pragma unroll
      for (int r = 0; r < 4; ++r) {
        int o = (wid * 4 + mt) * 16 + quad * 4 + r;
        g2v[mt][r] = g2[o];
        b2v[mt][r] = b2[o];
      }
#pragma unroll
    for (int nt = 0; nt < 4; ++nt) {
      int t = nt * 16 + col;
      float mean = stat[t], rstd = stat[64 + t];
#pragma unroll
      for (int mt = 0; mt < 4; ++mt) {
        int o = (wid * 4 + mt) * 16 + quad * 4;
        U4 wv;
#pragma unroll
        for (int r = 0; r < 4; ++r) {
          float u = (acc[mt][nt][r] - mean) * rstd * g2v[mt][r] + b2v[mt][r];
          wv.u[r] = f2bf(gelu_f(u));
        }
        *(uint2*)&y1b[t * 264 + o] = wv.v;
      }
    }
  }
  __syncthreads();
  // ---- Phase E: coalesced residual + store ----
#pragma unroll
  for (int p = 0; p < 8; ++p) {
    int idx = tid + p * 256;
    int trow = idx >> 5, cc = (idx & 31) * 8;
    int t = t0 + trow;
    U8 yv, rv, wv;
    yv.v = *(const uint4*)&y1b[trow * 264 + cc];
    rv.v = *(const uint4*)(hb + (size_t)t * F_ + cc);
    float mval = MASK_OUT ? mrow[t] : 1.f;
#pragma unroll
    for (int i = 0; i < 8; ++i) {
      float hv = bf2f(rv.u[i]) + bf2f(yv.u[i]);
      wv.u[i] = f2bf(MASK_OUT ? hv * mval : hv);
    }
    *(uint4*)(hT_out + ((size_t)b * T_ + t) * F_ + cc) = wv.v;
  }
}

// ---------------------------------------------------------------------------
// K3: proj GEMM (single-bf16) + RQ spline + logdet  (unchanged from r5)
// ---------------------------------------------------------------------------
__global__ __launch_bounds__(256, 4) void proj_spline_k(
    const ushort* __restrict__ hT,
    const float* __restrict__ x, const float* __restrict__ mask,
    const ushort* __restrict__ w_bf, const float* __restrict__ pb,
    float* __restrict__ out, float* __restrict__ logdet) {
  __shared__ __align__(16) ushort bsm[64 * 264];
  __shared__ float red[4];
  ushort* s_lds = bsm;

  int tid = threadIdx.x;
  int t0 = blockIdx.x * 64;
  int chunk = blockIdx.y;
  int b = blockIdx.z;
  int lane = tid & 63, wid = tid >> 6, col = lane & 15, quad = lane >> 4;

#pragma unroll
  for (int p = 0; p < 8; ++p) {
    int idx = tid + p * 256;
    int row = idx >> 5;
    int u = idx & 31;
    *(uint4*)(bsm + row * 264 + u * 8) =
        *(const uint4*)(hT + ((size_t)b * T_ + t0 + row) * F_ + u * 8);
  }
  f32x4 acc[4][4];
#pragma unroll
  for (int mt = 0; mt < 4; ++mt)
#pragma unroll
    for (int nt = 0; nt < 4; ++nt) acc[mt][nt] = (f32x4)(0.f);
  int rowA[4];
#pragma unroll
  for (int mt = 0; mt < 4; ++mt) {
    int r = chunk * 232 + (wid * 4 + mt) * 16 + col;
    rowA[mt] = r > 2783 ? 2783 : r;
  }
  __syncthreads();
#pragma unroll 1
  for (int ks = 0; ks < 8; ++ks) {
    int kloc = ks * 32 + quad * 8;
    s16x8 av[4];
#pragma unroll
    for (int mt = 0; mt < 4; ++mt)
      av[mt] = *(const s16x8*)(w_bf + (size_t)rowA[mt] * F_ + kloc);
#pragma unroll
    for (int nt = 0; nt < 4; ++nt) {
      s16x8 bv = *(const s16x8*)(bsm + (nt * 16 + col) * 264 + kloc);
#pragma unroll
      for (int mt = 0; mt < 4; ++mt)
        acc[mt][nt] = __builtin_amdgcn_mfma_f32_16x16x32_bf16(av[mt], bv, acc[mt][nt], 0, 0, 0);
    }
  }
  __syncthreads();
  {
    float mv[4];
#pragma unroll
    for (int nt = 0; nt < 4; ++nt)
      mv[nt] = mask[(size_t)b * T_ + t0 + nt * 16 + col];
#pragma unroll
    for (int mt = 0; mt < 4; ++mt) {
#pragma unroll
      for (int r = 0; r < 4; ++r) {
        int local = (wid * 4 + mt) * 16 + quad * 4 + r;
        if (local < 232) {
          float bias = pb[chunk * 232 + local];
#pragma unroll
          for (int nt = 0; nt < 4; ++nt)
            s_lds[local * 68 + nt * 16 + col] =
                f2bf((acc[mt][nt][r] + bias) * mv[nt]);
        }
      }
    }
  }
  __syncthreads();
  float lad_sum = 0.f;
  int ch_i = tid >> 5, ti = tid & 31;
  int ch = chunk * 8 + ch_i;
#pragma unroll 1
  for (int pass = 0; pass < 2; ++pass) {
    int t = ti + pass * 32;
    float s[29];
#pragma unroll
    for (int j = 0; j < 29; ++j) s[j] = bf2f(s_lds[(ch_i * 29 + j) * 68 + t]);
    float xin = x[((size_t)b * C_ + HALF_ + ch) * T_ + t0 + t];
    float mval = mask[(size_t)b * T_ + t0 + t];
    float ew[10];
    float esum = 0.f;
#pragma unroll
    for (int j = 0; j < 10; ++j) { ew[j] = __expf(s[j] * 0.0625f); esum += ew[j]; }
    float inv = 1.f / esum;
    float cw[11];
    cw[0] = -5.f;
    float csum = 0.f;
#pragma unroll
    for (int j = 0; j < 9; ++j) {
      csum += fmaf(0.99f, ew[j] * inv, 0.001f);
      cw[j + 1] = fmaf(10.f, csum, -5.f);
    }
    cw[10] = 5.f;
    float eh[10];
    esum = 0.f;
#pragma unroll
    for (int j = 0; j < 10; ++j) { eh[j] = __expf(s[10 + j] * 0.0625f); esum += eh[j]; }
    inv = 1.f / esum;
    float chh[11];
    chh[0] = -5.f;
    csum = 0.f;
#pragma unroll
    for (int j = 0; j < 9; ++j) {
      csum += fmaf(0.99f, eh[j] * inv, 0.001f);
      chh[j + 1] = fmaf(10.f, csum, -5.f);
    }
    chh[10] = 5.f;
    float dv[11];
    dv[0] = 1.f; dv[10] = 1.f;
#pragma unroll
    for (int j = 1; j < 10; ++j) {
      float u = s[19 + j];
      float sp = (u > 15.f) ? u : __logf(1.f + __expf(u));
      dv[j] = 0.001f + sp;
    }
    float xc = fminf(fmaxf(xin, -5.f), 5.f);
    bool inside = (xin >= -5.f) && (xin <= 5.f);
    int idx = 0;
#pragma unroll
    for (int k = 1; k <= 10; ++k) idx += (xc >= cw[k]) ? 1 : 0;
    idx = idx > 9 ? 9 : idx;
    float in_cw = cw[0], in_w = cw[1] - cw[0];
    float in_ch = chh[0], in_h = chh[1] - chh[0];
    float d0 = dv[0], d1 = dv[1];
#pragma unroll
    for (int k = 1; k < 10; ++k) {
      bool sel = (idx == k);
      in_cw = sel ? cw[k] : in_cw;
      in_w = sel ? (cw[k + 1] - cw[k]) : in_w;
      in_ch = sel ? chh[k] : in_ch;
      in_h = sel ? (chh[k + 1] - chh[k]) : in_h;
      d0 = sel ? dv[k] : d0;
      d1 = sel ? dv[k + 1] : d1;
    }
    float theta = (xc - in_cw) / in_w;
    float delta = in_h / in_w;
    float omt = 1.f - theta;
    float t1m = theta * omt;
    float th2 = theta * theta;
    float denom = delta + (d0 + d1 - 2.f * delta) * t1m;
    float num = in_h * (delta * th2 + d0 * t1m);
    float outv = in_ch + num / denom;
    float dnum = delta * delta * (d1 * th2 + 2.f * delta * t1m + d0 * omt * omt);
    float lad = __logf(dnum) - 2.f * __logf(denom);
    float res = inside ? outv : xin;
    float ladv = inside ? lad : 0.f;
    out[((size_t)b * C_ + HALF_ + ch) * T_ + t0 + t] = res * mval;
    lad_sum += ladv * mval;
  }
#pragma unroll
  for (int off = 32; off > 0; off >>= 1)
    lad_sum += __shfl_down(lad_sum, off, 64);
  if ((tid & 63) == 0) red[tid >> 6] = lad_sum;
  __syncthreads();
  if (tid == 0)
    atomicAdd(logdet + b, red[0] + red[1] + red[2] + red[3]);
}

// ---------------------------------------------------------------------------
// K4: out[:, :96, :] = x0 * mask
// ---------------------------------------------------------------------------
__global__ void copy_x0_k(const float* __restrict__ x,
                          const float* __restrict__ mask,
                          float* __restrict__ out) {
  int i = blockIdx.x * 256 + threadIdx.x;
  int b = i / (HALF_ * T_ / 4);
  int r = i - b * (HALF_ * T_ / 4);
  int t4 = r & (T_ / 4 - 1);
  float4 v = ((const float4*)(x + (size_t)b * C_ * T_))[r];
  float4 m = ((const float4*)(mask + (size_t)b * T_))[t4];
  v.x *= m.x; v.y *= m.y; v.z *= m.z; v.w *= m.w;
  ((float4*)(out + (size_t)b * C_ * T_))[r] = v;
}

extern "C" void kernel_launch(void* const* d_in, const int* in_sizes, int n_in,
                              void* d_out, int out_size, void* d_ws, size_t ws_size,
                              hipStream_t stream) {
  const float* x      = (const float*)d_in[0];
  const float* mask   = (const float*)d_in[1];
  const float* pre_w  = (const float*)d_in[2];
  const float* pre_b  = (const float*)d_in[3];
  const float* dw_w   = (const float*)d_in[4];
  const float* dw_b   = (const float*)d_in[5];
  const float* pw_w   = (const float*)d_in[6];
  const float* pw_b   = (const float*)d_in[7];
  const float* g1     = (const float*)d_in[8];
  const float* b1     = (const float*)d_in[9];
  const float* g2     = (const float*)d_in[10];
  const float* b2     = (const float*)d_in[11];
  const float* proj_w = (const float*)d_in[12];
  const float* proj_b = (const float*)d_in[13];
  float* out = (float*)d_out;
  float* logdet = out + (size_t)B_ * C_ * T_;

  const size_t HSZ = (size_t)B_ * T_ * F_;   // 8.39M bf16 elems
  ushort* hA    = (ushort*)d_ws;
  ushort* hB    = hA + HSZ;
  ushort* wprj  = hB + HSZ;                  // 2784*256
  ushort* wpw   = wprj + 2784 * 256;         // 3*256*256
  ushort* wpre  = wpw + 3 * F_ * F_;         // 256*96

  hipMemsetAsync(logdet, 0, B_ * sizeof(float), stream);
  wcvt_k<<<dim3((2784 * 256 + 255) / 256), 256, 0, stream>>>(proj_w, wprj, 2784 * 256);
  wcvt_k<<<dim3((3 * F_ * F_ + 255) / 256), 256, 0, stream>>>(pw_w, wpw, 3 * F_ * F_);
  wcvt_k<<<dim3((F_ * HALF_ + 255) / 256), 256, 0, stream>>>(pre_w, wpre, F_ * HALF_);

  pre_k<<<dim3(T_ / 64, B_), 256, 0, stream>>>(x, wpre, pre_b, hA);

  layer_k<false><<<dim3(T_ / 64, B_), 256, 0, stream>>>(hA, hB, mask,
      dw_w, dw_b, g1, b1, wpw, pw_b, g2, b2, 1);
  layer_k<false><<<dim3(T_ / 64, B_), 256, 0, stream>>>(hB, hA, mask,
      dw_w + F_ * 3, dw_b + F_, g1 + F_, b1 + F_,
      wpw + F_ * F_, pw_b + F_, g2 + F_, b2 + F_, 3);
  layer_k<true><<<dim3(T_ / 64, B_), 256, 0, stream>>>(hA, hB, mask,
      dw_w + 2 * F_ * 3, dw_b + 2 * F_, g1 + 2 * F_, b1 + 2 * F_,
      wpw + 2 * F_ * F_, pw_b + 2 * F_, g2 + 2 * F_, b2 + 2 * F_, 9);

  copy_x0_k<<<dim3(B_ * HALF_ * T_ / 4 / 256), 256, 0, stream>>>(x, mask, out);
  proj_spline_k<<<dim3(T_ / 64, 12, B_), 256, 0, stream>>>(hB, x, mask,
      wprj, proj_b, out, logdet);
}

// Round 7
// 382.082 us; speedup vs baseline: 1.7684x; 1.0855x over previous
//
#include <hip/hip_runtime.h>

#define B_ 16
#define C_ 192
#define T_ 2048
#define F_ 256
#define HALF_ 96

typedef short s16x8 __attribute__((ext_vector_type(8)));
typedef float f32x4 __attribute__((ext_vector_type(4)));
typedef unsigned short ushort;

union U8 { uint4 v; ushort u[8]; };
union U4 { uint2 v; ushort u[4]; };

__device__ __forceinline__ ushort f2bf(float f) {
  unsigned u = __float_as_uint(f);
  unsigned r = u + 0x7fff + ((u >> 16) & 1);
  return (ushort)(r >> 16);
}
__device__ __forceinline__ float bf2f(ushort h) {
  return __uint_as_float(((unsigned)h) << 16);
}
// tanh-form gelu (~12 insts vs ~35 for erff); abs error ~3e-3, within budget
__device__ __forceinline__ float gelu_f(float x) {
  float x3 = x * x * x;
  float z = fmaf(0.0356774081f, x3, 0.7978845608f * x);
  float az = fabsf(z);
  float e = __expf(-2.f * az);
  float th = (1.f - e) * __builtin_amdgcn_rcpf(1.f + e);
  th = copysignf(th, z);
  return 0.5f * x * (1.f + th);
}

// ---------------------------------------------------------------------------
// wcvt_pp: pw (3*F*F) then pre (F*96) fp32 -> bf16
// ---------------------------------------------------------------------------
__global__ void wcvt_pp_k(const float* __restrict__ pw_w,
                          const float* __restrict__ pre_w,
                          ushort* __restrict__ wpw, ushort* __restrict__ wpre) {
  int i = blockIdx.x * 256 + threadIdx.x;
  const int n1 = 3 * F_ * F_;
  if (i < n1) {
    wpw[i] = f2bf(pw_w[i]);
  } else if (i < n1 + F_ * HALF_) {
    int j = i - n1;
    wpre[j] = f2bf(pre_w[j]);
  }
}

// ---------------------------------------------------------------------------
// wcvt_prj: proj_w fp32 -> bf16, rows PERMUTED within each 232-chunk so that
// local row (j*8 + ch_i) holds original (ch_i*29 + j).  bias permuted too.
// ---------------------------------------------------------------------------
__global__ void wcvt_prj_k(const float* __restrict__ w, const float* __restrict__ pb,
                           ushort* __restrict__ wp, float* __restrict__ pbp) {
  int i = blockIdx.x * 256 + threadIdx.x;
  if (i >= 2784 * 256) return;
  int r = i >> 8, k = i & 255;
  int chunk = r / 232;
  int wloc = r - chunk * 232;
  int ch_i = wloc / 29;
  int j = wloc - ch_i * 29;
  int pr = chunk * 232 + j * 8 + ch_i;
  wp[(size_t)pr * 256 + k] = f2bf(w[i]);
  if (k == 0) pbp[pr] = pb[r];
}

// ---------------------------------------------------------------------------
// K1: pre GEMM via MFMA, 32-t tiles. x0 fp32 [c][t] -> hT bf16 [b][t][c]
// ---------------------------------------------------------------------------
__global__ __launch_bounds__(256, 4) void pre_k(
    const float* __restrict__ x, const ushort* __restrict__ wb,  // [256][96]
    const float* __restrict__ pb, ushort* __restrict__ hT) {
  __shared__ ushort xb[32 * 104];
  __shared__ __align__(16) ushort ob[32 * 264];
  int tid = threadIdx.x;
  int b = blockIdx.y;
  int t0 = blockIdx.x * 32;
#pragma unroll
  for (int p = 0; p < 12; ++p) {
    int idx = tid + p * 256;          // 96*32 = 3072
    int c = idx >> 5, t = idx & 31;
    xb[t * 104 + c] = f2bf(x[((size_t)b * C_ + c) * T_ + t0 + t]);
  }
  __syncthreads();
  int lane = tid & 63, wid = tid >> 6, col = lane & 15, quad = lane >> 4;
  f32x4 acc[4][2];
#pragma unroll
  for (int mt = 0; mt < 4; ++mt)
#pragma unroll
    for (int nt = 0; nt < 2; ++nt) acc[mt][nt] = (f32x4)(0.f);
#pragma unroll
  for (int ks = 0; ks < 3; ++ks) {
    int kloc = ks * 32 + quad * 8;
    s16x8 av[4];
#pragma unroll
    for (int mt = 0; mt < 4; ++mt)
      av[mt] = *(const s16x8*)(wb + (size_t)((wid * 4 + mt) * 16 + col) * 96 + kloc);
#pragma unroll
    for (int nt = 0; nt < 2; ++nt) {
      s16x8 bv = *(const s16x8*)(xb + (nt * 16 + col) * 104 + kloc);
#pragma unroll
      for (int mt = 0; mt < 4; ++mt)
        acc[mt][nt] = __builtin_amdgcn_mfma_f32_16x16x32_bf16(av[mt], bv, acc[mt][nt], 0, 0, 0);
    }
  }
  float pbv[4][4];
#pragma unroll
  for (int mt = 0; mt < 4; ++mt)
    *(float4*)pbv[mt] = *(const float4*)(pb + (wid * 4 + mt) * 16 + quad * 4);
#pragma unroll
  for (int nt = 0; nt < 2; ++nt) {
    int t = nt * 16 + col;
#pragma unroll
    for (int mt = 0; mt < 4; ++mt) {
      int o = (wid * 4 + mt) * 16 + quad * 4;
      U4 wv;
#pragma unroll
      for (int r = 0; r < 4; ++r) wv.u[r] = f2bf(acc[mt][nt][r] + pbv[mt][r]);
      *(uint2*)&ob[t * 264 + o] = wv.v;
    }
  }
  __syncthreads();
#pragma unroll
  for (int p = 0; p < 4; ++p) {
    int idx = tid + p * 256;
    int trow = idx >> 5, cc = (idx & 31) * 8;
    *(uint4*)(hT + ((size_t)b * T_ + t0 + trow) * F_ + cc) =
        *(const uint4*)&ob[trow * 264 + cc];
  }
}

// ---------------------------------------------------------------------------
// K2: fused layer, 32-t tiles (grid 1024 -> 4 blocks/CU).
// ---------------------------------------------------------------------------
template <bool MASK_OUT>
__global__ __launch_bounds__(256, 4) void layer_k(
    const ushort* __restrict__ hT_in, ushort* __restrict__ hT_out,
    const float* __restrict__ mask,
    const float* __restrict__ dww, const float* __restrict__ dwb,
    const float* __restrict__ g1, const float* __restrict__ b1,
    const ushort* __restrict__ pw, const float* __restrict__ pwb,
    const float* __restrict__ g2, const float* __restrict__ b2,
    int dil) {
  __shared__ __align__(16) ushort y1b[32 * 264];  // [t][c] bf16 (16.9 KB)
  __shared__ float stat[64];
  float* scratch = (float*)y1b;  // overlay post-GEMM
  int tid = threadIdx.x;
  int b = blockIdx.y;
  int t0 = blockIdx.x * 32;
  const ushort* hb = hT_in + (size_t)b * T_ * F_;
  const float* mrow = mask + (size_t)b * T_;

  // ---- Phase A: conv + norm1 + gelu (lanes over channels, shfl stats) ----
  {
    int lane32 = tid & 31;
    int half = tid >> 5;          // 0..7
    int c0 = lane32 * 8;
    float dwl[24], dbv[8], g1v[8], b1v[8];
#pragma unroll
    for (int q = 0; q < 6; ++q)
      *(float4*)&dwl[q * 4] = *(const float4*)(dww + c0 * 3 + q * 4);
    *(float4*)&dbv[0] = *(const float4*)(dwb + c0);
    *(float4*)&dbv[4] = *(const float4*)(dwb + c0 + 4);
    *(float4*)&g1v[0] = *(const float4*)(g1 + c0);
    *(float4*)&g1v[4] = *(const float4*)(g1 + c0 + 4);
    *(float4*)&b1v[0] = *(const float4*)(b1 + c0);
    *(float4*)&b1v[4] = *(const float4*)(b1 + c0 + 4);
    uint4 zero4 = make_uint4(0, 0, 0, 0);
#pragma unroll 1
    for (int pass = 0; pass < 4; ++pass) {
      int t = pass * 8 + half;
      int tz = t0 + t, tm = tz - dil, tp = tz + dil;
      bool vm = (tm >= 0), vp = (tp < T_);
      float mm = vm ? mrow[tm] : 0.f;
      float mz = mrow[tz];
      float mp = vp ? mrow[tp] : 0.f;
      U8 r0, r1, r2;
      r0.v = vm ? *(const uint4*)(hb + (size_t)tm * F_ + c0) : zero4;
      r1.v = *(const uint4*)(hb + (size_t)tz * F_ + c0);
      r2.v = vp ? *(const uint4*)(hb + (size_t)tp * F_ + c0) : zero4;
      float v[8];
      float s = 0.f, q = 0.f;
#pragma unroll
      for (int i = 0; i < 8; ++i) {
        float vv = fmaf(dwl[i * 3], bf2f(r0.u[i]) * mm,
                   fmaf(dwl[i * 3 + 1], bf2f(r1.u[i]) * mz,
                   fmaf(dwl[i * 3 + 2], bf2f(r2.u[i]) * mp, dbv[i])));
        v[i] = vv;
        s += vv;
        q = fmaf(vv, vv, q);
      }
#pragma unroll
      for (int m = 1; m < 32; m <<= 1) {
        s += __shfl_xor(s, m, 32);
        q += __shfl_xor(q, m, 32);
      }
      float mean = s * (1.f / 256.f);
      float var = q * (1.f / 256.f) - mean * mean;
      float rstd = rsqrtf(var + 1e-5f);
      U8 pk;
#pragma unroll
      for (int i = 0; i < 8; ++i) {
        float u = (v[i] - mean) * rstd * g1v[i] + b1v[i];
        pk.u[i] = f2bf(gelu_f(u));
      }
      *(uint4*)&y1b[t * 264 + c0] = pk.v;
    }
  }
  __syncthreads();
  // ---- Phase B: MFMA GEMM  W(256x256) @ y1(256k x 32t) ----
  int lane = tid & 63, wid = tid >> 6, col = lane & 15, quad = lane >> 4;
  f32x4 acc[4][2];
#pragma unroll
  for (int mt = 0; mt < 4; ++mt)
#pragma unroll
    for (int nt = 0; nt < 2; ++nt) acc[mt][nt] = (f32x4)(0.f);
#pragma unroll 1
  for (int ks = 0; ks < 8; ++ks) {
    int kloc = ks * 32 + quad * 8;
    s16x8 av[4];
#pragma unroll
    for (int mt = 0; mt < 4; ++mt)
      av[mt] = *(const s16x8*)(pw + (size_t)((wid * 4 + mt) * 16 + col) * F_ + kloc);
#pragma unroll
    for (int nt = 0; nt < 2; ++nt) {
      s16x8 bv = *(const s16x8*)(y1b + (nt * 16 + col) * 264 + kloc);
#pragma unroll
      for (int mt = 0; mt < 4; ++mt)
        acc[mt][nt] = __builtin_amdgcn_mfma_f32_16x16x32_bf16(av[mt], bv, acc[mt][nt], 0, 0, 0);
    }
  }
  __syncthreads();  // y1b reads done -> scratch overlay safe
  // ---- Phase C: bias + per-t stats ----
  float pwbv[4][4];
#pragma unroll
  for (int mt = 0; mt < 4; ++mt)
    *(float4*)pwbv[mt] = *(const float4*)(pwb + (wid * 4 + mt) * 16 + quad * 4);
#pragma unroll
  for (int nt = 0; nt < 2; ++nt) {
    float s = 0.f, q = 0.f;
#pragma unroll
    for (int mt = 0; mt < 4; ++mt)
#pragma unroll
      for (int r = 0; r < 4; ++r) {
        float v = acc[mt][nt][r] + pwbv[mt][r];
        acc[mt][nt][r] = v;
        s += v;
        q = fmaf(v, v, q);
      }
    int pcol = (wid * 4 + quad) * 32 + nt * 16 + col;
    scratch[pcol] = s;
    scratch[512 + pcol] = q;
  }
  __syncthreads();
  if (tid < 32) {
    float s = 0.f, q = 0.f;
#pragma unroll
    for (int p = 0; p < 16; ++p) {
      s += scratch[p * 32 + tid];
      q += scratch[512 + p * 32 + tid];
    }
    float mean = s * (1.f / 256.f);
    float var = q * (1.f / 256.f) - mean * mean;
    stat[tid] = mean;
    stat[32 + tid] = rsqrtf(var + 1e-5f);
  }
  __syncthreads();
  // ---- Phase D: norm2 + gelu -> y1b bf16 [t][c] ----
  {
    float g2v[4][4], b2v[4][4];
#pragma unroll
    for (int mt = 0; mt < 4; ++mt) {
      *(float4*)g2v[mt] = *(const float4*)(g2 + (wid * 4 + mt) * 16 + quad * 4);
      *(float4*)b2v[mt] = *(const float4*)(b2 + (wid * 4 + mt) * 16 + quad * 4);
    }
#pragma unroll
    for (int nt = 0; nt < 2; ++nt) {
      int t = nt * 16 + col;
      float mean = stat[t], rstd = stat[32 + t];
#pragma unroll
      for (int mt = 0; mt < 4; ++mt) {
        int o = (wid * 4 + mt) * 16 + quad * 4;
        U4 wv;
#pragma unroll
        for (int r = 0; r < 4; ++r) {
          float u = (acc[mt][nt][r] - mean) * rstd * g2v[mt][r] + b2v[mt][r];
          wv.u[r] = f2bf(gelu_f(u));
        }
        *(uint2*)&y1b[t * 264 + o] = wv.v;
      }
    }
  }
  __syncthreads();
  // ---- Phase E: coalesced residual + store ----
#pragma unroll
  for (int p = 0; p < 4; ++p) {
    int idx = tid + p * 256;
    int trow = idx >> 5, cc = (idx & 31) * 8;
    int t = t0 + trow;
    U8 yv, rv, wv;
    yv.v = *(const uint4*)&y1b[trow * 264 + cc];
    rv.v = *(const uint4*)(hb + (size_t)t * F_ + cc);
    float mval = MASK_OUT ? mrow[t] : 1.f;
#pragma unroll
    for (int i = 0; i < 8; ++i) {
      float hv = bf2f(rv.u[i]) + bf2f(yv.u[i]);
      wv.u[i] = f2bf(MASK_OUT ? hv * mval : hv);
    }
    *(uint4*)(hT_out + ((size_t)b * T_ + t) * F_ + cc) = wv.v;
  }
}

// ---------------------------------------------------------------------------
// K3: proj GEMM (bf16, permuted rows) + RQ spline + logdet + x0-copy
// grid (T/64, 12, B); block 256.  s-tile [8 ch][64 t][36] bf16 (36.9 KB).
// ---------------------------------------------------------------------------
__global__ __launch_bounds__(256, 4) void proj_spline_k(
    const ushort* __restrict__ hT,
    const float* __restrict__ x, const float* __restrict__ mask,
    const ushort* __restrict__ w_bf, const float* __restrict__ pbp,
    float* __restrict__ out, float* __restrict__ logdet) {
  __shared__ __align__(16) ushort bsm[8 * 64 * 36];  // union B-tile / s-tile
  __shared__ float red[4];
  ushort* s_lds = bsm;

  int tid = threadIdx.x;
  int t0 = blockIdx.x * 64;
  int chunk = blockIdx.y;
  int b = blockIdx.z;
  int lane = tid & 63, wid = tid >> 6, col = lane & 15, quad = lane >> 4;

  // stage B-tile [row t][264] (rows 0..63, K=256)
#pragma unroll
  for (int p = 0; p < 8; ++p) {
    int idx = tid + p * 256;
    int row = idx >> 5;
    int u = idx & 31;
    *(uint4*)(bsm + row * 264 + u * 8) =
        *(const uint4*)(hT + ((size_t)b * T_ + t0 + row) * F_ + u * 8);
  }
  // folded x0-copy: this chunk handles channels chunk*8..chunk*8+7
#pragma unroll
  for (int p = 0; p < 2; ++p) {
    int idx = tid + p * 256;
    int ch = idx >> 6, t = idx & 63;
    out[((size_t)b * C_ + chunk * 8 + ch) * T_ + t0 + t] =
        x[((size_t)b * C_ + chunk * 8 + ch) * T_ + t0 + t] * mask[(size_t)b * T_ + t0 + t];
  }
  f32x4 acc[4][4];
#pragma unroll
  for (int mt = 0; mt < 4; ++mt)
#pragma unroll
    for (int nt = 0; nt < 4; ++nt) acc[mt][nt] = (f32x4)(0.f);
  int rowA[4];
#pragma unroll
  for (int mt = 0; mt < 4; ++mt) {
    int r = chunk * 232 + (wid * 4 + mt) * 16 + col;
    rowA[mt] = r > 2783 ? 2783 : r;
  }
  __syncthreads();
#pragma unroll 1
  for (int ks = 0; ks < 8; ++ks) {
    int kloc = ks * 32 + quad * 8;
    s16x8 av[4];
#pragma unroll
    for (int mt = 0; mt < 4; ++mt)
      av[mt] = *(const s16x8*)(w_bf + (size_t)rowA[mt] * F_ + kloc);
#pragma unroll
    for (int nt = 0; nt < 4; ++nt) {
      s16x8 bv = *(const s16x8*)(bsm + (nt * 16 + col) * 264 + kloc);
#pragma unroll
      for (int mt = 0; mt < 4; ++mt)
        acc[mt][nt] = __builtin_amdgcn_mfma_f32_16x16x32_bf16(av[mt], bv, acc[mt][nt], 0, 0, 0);
    }
  }
  __syncthreads();
  // ---- write s-tile: local = j*8+ch_i (permuted rows) -> [ch][t][36] ----
  {
    float mv[4];
#pragma unroll
    for (int nt = 0; nt < 4; ++nt)
      mv[nt] = mask[(size_t)b * T_ + t0 + nt * 16 + col];
#pragma unroll
    for (int mt = 0; mt < 4; ++mt) {
#pragma unroll
      for (int r = 0; r < 4; ++r) {
        int local = (wid * 4 + mt) * 16 + quad * 4 + r;
        if (local < 232) {
          int ch_i = local & 7, j = local >> 3;
          float bias = pbp[chunk * 232 + local];
#pragma unroll
          for (int nt = 0; nt < 4; ++nt)
            s_lds[ch_i * 2304 + (nt * 16 + col) * 36 + j] =
                f2bf((acc[mt][nt][r] + bias) * mv[nt]);
        }
      }
    }
  }
  __syncthreads();
  // ---- spline: 8 ch x 64 t per block; 2 elements per thread ----
  float lad_sum = 0.f;
  int ch_i = tid >> 5, ti = tid & 31;
  int ch = chunk * 8 + ch_i;
#pragma unroll 1
  for (int pass = 0; pass < 2; ++pass) {
    int t = ti + pass * 32;
    const ushort* sp = s_lds + ch_i * 2304 + t * 36;
    float s[29];
#pragma unroll
    for (int jj = 0; jj < 7; ++jj) {
      U4 w;
      w.v = *(const uint2*)(sp + jj * 4);
      s[jj * 4 + 0] = bf2f(w.u[0]);
      s[jj * 4 + 1] = bf2f(w.u[1]);
      s[jj * 4 + 2] = bf2f(w.u[2]);
      s[jj * 4 + 3] = bf2f(w.u[3]);
    }
    s[28] = bf2f(sp[28]);
    float xin = x[((size_t)b * C_ + HALF_ + ch) * T_ + t0 + t];
    float mval = mask[(size_t)b * T_ + t0 + t];
    // widths: exp2(s * 0.0625*log2e) fused scale
    const float KE = 0.09016844f;
    float ew[10];
    float esum = 0.f;
#pragma unroll
    for (int j = 0; j < 10; ++j) { ew[j] = exp2f(s[j] * KE); esum += ew[j]; }
    float inv = __builtin_amdgcn_rcpf(esum);
    float cw[11];
    cw[0] = -5.f;
    float csum = 0.f;
#pragma unroll
    for (int j = 0; j < 9; ++j) {
      csum += fmaf(0.99f, ew[j] * inv, 0.001f);
      cw[j + 1] = fmaf(10.f, csum, -5.f);
    }
    cw[10] = 5.f;
    float eh[10];
    esum = 0.f;
#pragma unroll
    for (int j = 0; j < 10; ++j) { eh[j] = exp2f(s[10 + j] * KE); esum += eh[j]; }
    inv = __builtin_amdgcn_rcpf(esum);
    float chh[11];
    chh[0] = -5.f;
    csum = 0.f;
#pragma unroll
    for (int j = 0; j < 9; ++j) {
      csum += fmaf(0.99f, eh[j] * inv, 0.001f);
      chh[j + 1] = fmaf(10.f, csum, -5.f);
    }
    chh[10] = 5.f;
    float dv[11];
    dv[0] = 1.f; dv[10] = 1.f;
#pragma unroll
    for (int j = 1; j < 10; ++j) {
      float u = s[19 + j];
      float sp_ = (u > 15.f) ? u : __logf(1.f + __expf(u));
      dv[j] = 0.001f + sp_;
    }
    float xc = fminf(fmaxf(xin, -5.f), 5.f);
    bool inside = (xin >= -5.f) && (xin <= 5.f);
    int idx = 0;
#pragma unroll
    for (int k = 1; k <= 10; ++k) idx += (xc >= cw[k]) ? 1 : 0;
    idx = idx > 9 ? 9 : idx;
    float in_cw = cw[0], in_w = cw[1] - cw[0];
    float in_ch = chh[0], in_h = chh[1] - chh[0];
    float d0 = dv[0], d1 = dv[1];
#pragma unroll
    for (int k = 1; k < 10; ++k) {
      bool sel = (idx == k);
      in_cw = sel ? cw[k] : in_cw;
      in_w = sel ? (cw[k + 1] - cw[k]) : in_w;
      in_ch = sel ? chh[k] : in_ch;
      in_h = sel ? (chh[k + 1] - chh[k]) : in_h;
      d0 = sel ? dv[k] : d0;
      d1 = sel ? dv[k + 1] : d1;
    }
    float rw = __builtin_amdgcn_rcpf(in_w);
    float theta = (xc - in_cw) * rw;
    float delta = in_h * rw;
    float omt = 1.f - theta;
    float t1m = theta * omt;
    float th2 = theta * theta;
    float denom = delta + (d0 + d1 - 2.f * delta) * t1m;
    float rd = __builtin_amdgcn_rcpf(denom);
    float num = in_h * (delta * th2 + d0 * t1m);
    float outv = in_ch + num * rd;
    float dnum = delta * delta * (d1 * th2 + 2.f * delta * t1m + d0 * omt * omt);
    float lad = __logf(dnum * rd * rd);
    float res = inside ? outv : xin;
    float ladv = inside ? lad : 0.f;
    out[((size_t)b * C_ + HALF_ + ch) * T_ + t0 + t] = res * mval;
    lad_sum += ladv * mval;
  }
#pragma unroll
  for (int off = 32; off > 0; off >>= 1)
    lad_sum += __shfl_down(lad_sum, off, 64);
  if ((tid & 63) == 0) red[tid >> 6] = lad_sum;
  __syncthreads();
  if (tid == 0)
    atomicAdd(logdet + b, red[0] + red[1] + red[2] + red[3]);
}

extern "C" void kernel_launch(void* const* d_in, const int* in_sizes, int n_in,
                              void* d_out, int out_size, void* d_ws, size_t ws_size,
                              hipStream_t stream) {
  const float* x      = (const float*)d_in[0];
  const float* mask   = (const float*)d_in[1];
  const float* pre_w  = (const float*)d_in[2];
  const float* pre_b  = (const float*)d_in[3];
  const float* dw_w   = (const float*)d_in[4];
  const float* dw_b   = (const float*)d_in[5];
  const float* pw_w   = (const float*)d_in[6];
  const float* pw_b   = (const float*)d_in[7];
  const float* g1     = (const float*)d_in[8];
  const float* b1     = (const float*)d_in[9];
  const float* g2     = (const float*)d_in[10];
  const float* b2     = (const float*)d_in[11];
  const float* proj_w = (const float*)d_in[12];
  const float* proj_b = (const float*)d_in[13];
  float* out = (float*)d_out;
  float* logdet = out + (size_t)B_ * C_ * T_;

  const size_t HSZ = (size_t)B_ * T_ * F_;   // 8.39M bf16 elems
  ushort* hA    = (ushort*)d_ws;
  ushort* hB    = hA + HSZ;
  ushort* wprj  = hB + HSZ;                  // 2784*256
  ushort* wpw   = wprj + 2784 * 256;         // 3*256*256
  ushort* wpre  = wpw + 3 * F_ * F_;         // 256*96
  float*  pbp   = (float*)(wpre + F_ * HALF_);  // 2784 floats (permuted bias)

  hipMemsetAsync(logdet, 0, B_ * sizeof(float), stream);
  wcvt_prj_k<<<dim3((2784 * 256 + 255) / 256), 256, 0, stream>>>(proj_w, proj_b,
      wprj, pbp);
  wcvt_pp_k<<<dim3((3 * F_ * F_ + F_ * HALF_ + 255) / 256), 256, 0, stream>>>(
      pw_w, pre_w, wpw, wpre);

  pre_k<<<dim3(T_ / 32, B_), 256, 0, stream>>>(x, wpre, pre_b, hA);

  layer_k<false><<<dim3(T_ / 32, B_), 256, 0, stream>>>(hA, hB, mask,
      dw_w, dw_b, g1, b1, wpw, pw_b, g2, b2, 1);
  layer_k<false><<<dim3(T_ / 32, B_), 256, 0, stream>>>(hB, hA, mask,
      dw_w + F_ * 3, dw_b + F_, g1 + F_, b1 + F_,
      wpw + F_ * F_, pw_b + F_, g2 + F_, b2 + F_, 3);
  layer_k<true><<<dim3(T_ / 32, B_), 256, 0, stream>>>(hA, hB, mask,
      dw_w + 2 * F_ * 3, dw_b + 2 * F_, g1 + 2 * F_, b1 + 2 * F_,
      wpw + 2 * F_ * F_, pw_b + 2 * F_, g2 + 2 * F_, b2 + 2 * F_, 9);

  proj_spline_k<<<dim3(T_ / 64, 12, B_), 256, 0, stream>>>(hB, x, mask,
      wprj, pbp, out, logdet);
}

// Round 8
// 312.260 us; speedup vs baseline: 2.1639x; 1.2236x over previous
//
#include <hip/hip_runtime.h>

#define B_ 16
#define C_ 192
#define T_ 2048
#define F_ 256
#define HALF_ 96

typedef short s16x8 __attribute__((ext_vector_type(8)));
typedef float f32x4 __attribute__((ext_vector_type(4)));
typedef unsigned short ushort;

union U8 { uint4 v; ushort u[8]; };
union U4 { uint2 v; ushort u[4]; };

__device__ __forceinline__ ushort f2bf(float f) {
  unsigned u = __float_as_uint(f);
  unsigned r = u + 0x7fff + ((u >> 16) & 1);
  return (ushort)(r >> 16);
}
__device__ __forceinline__ float bf2f(ushort h) {
  return __uint_as_float(((unsigned)h) << 16);
}
// tanh-form gelu on raw v_exp_f32
__device__ __forceinline__ float gelu_f(float x) {
  float x3 = x * x * x;
  float z = fmaf(0.0356774081f, x3, 0.7978845608f * x);
  float az = fabsf(z);
  float e = __builtin_amdgcn_exp2f(az * -2.885390082f);  // exp(-2az)
  float th = (1.f - e) * __builtin_amdgcn_rcpf(1.f + e);
  th = copysignf(th, z);
  return 0.5f * x * (1.f + th);
}

// ---------------------------------------------------------------------------
// Weight converters -> MFMA-fragment order: wq[tile][ks][lane][8], so a wave's
// A-load is base + lane*16B (fully coalesced). lane = quad*16+col encodes
// row = tile*16+col, k = ks*32+quad*8+e.
// ---------------------------------------------------------------------------
__global__ void wcvt_prj_k(const float* __restrict__ w, const float* __restrict__ pb,
                           ushort* __restrict__ wq, float* __restrict__ pbp) {
  int d = blockIdx.x * 256 + threadIdx.x;   // 12*16*8*64*8 = 786432
  if (d >= 786432) return;
  int e = d & 7;
  int lane = (d >> 3) & 63;
  int ks = (d >> 9) & 7;
  int mtile = (d >> 12) & 15;
  int chunk = d >> 16;
  int col = lane & 15, quad = lane >> 4;
  int pr_loc = mtile * 16 + col;            // permuted local row = j*8+ch_i
  int k = ks * 32 + quad * 8 + e;
  float val = 0.f;
  if (pr_loc < 232) {
    int j = pr_loc >> 3, ch_i = pr_loc & 7;
    int r = chunk * 232 + ch_i * 29 + j;    // original row
    val = w[(size_t)r * 256 + k];
    if (ks == 0 && quad == 0 && e == 0) pbp[chunk * 232 + pr_loc] = pb[r];
  }
  wq[d] = f2bf(val);
}

__global__ void wcvt_pw_k(const float* __restrict__ pw_w, ushort* __restrict__ wq) {
  int d = blockIdx.x * 256 + threadIdx.x;   // 3*16*8*64*8 = 196608
  if (d >= 196608) return;
  int e = d & 7;
  int lane = (d >> 3) & 63;
  int ks = (d >> 9) & 7;
  int mtile = (d >> 12) & 15;
  int l = d >> 16;
  int col = lane & 15, quad = lane >> 4;
  int row = mtile * 16 + col, k = ks * 32 + quad * 8 + e;
  wq[d] = f2bf(pw_w[(size_t)(l * 256 + row) * 256 + k]);
}

__global__ void wcvt_pre_k(const float* __restrict__ pre_w, ushort* __restrict__ wq) {
  int d = blockIdx.x * 256 + threadIdx.x;   // 16*3*64*8 = 24576
  if (d >= 24576) return;
  int e = d & 7;
  int idx = d >> 3;
  int lane = idx & 63; idx >>= 6;
  int ks = idx % 3, mtile = idx / 3;
  int col = lane & 15, quad = lane >> 4;
  int row = mtile * 16 + col, k = ks * 32 + quad * 8 + e;
  wq[d] = f2bf(pre_w[row * 96 + k]);
}

// ---------------------------------------------------------------------------
// K1: pre GEMM via MFMA, 32-t tiles. x0 fp32 [c][t] -> hT bf16 [b][t][c]
// ---------------------------------------------------------------------------
__global__ __launch_bounds__(256, 4) void pre_k(
    const float* __restrict__ x, const ushort* __restrict__ wb,
    const float* __restrict__ pb, ushort* __restrict__ hT) {
  __shared__ ushort xb[32 * 104];
  __shared__ __align__(16) ushort ob[32 * 264];
  int tid = threadIdx.x;
  int b = blockIdx.y;
  int t0 = blockIdx.x * 32;
#pragma unroll
  for (int p = 0; p < 12; ++p) {
    int idx = tid + p * 256;
    int c = idx >> 5, t = idx & 31;
    xb[t * 104 + c] = f2bf(x[((size_t)b * C_ + c) * T_ + t0 + t]);
  }
  __syncthreads();
  int lane = tid & 63, wid = tid >> 6, col = lane & 15, quad = lane >> 4;
  f32x4 acc[4][2];
#pragma unroll
  for (int mt = 0; mt < 4; ++mt)
#pragma unroll
    for (int nt = 0; nt < 2; ++nt) acc[mt][nt] = (f32x4)(0.f);
#pragma unroll
  for (int ks = 0; ks < 3; ++ks) {
    int kloc = ks * 32 + quad * 8;
    s16x8 av[4];
#pragma unroll
    for (int mt = 0; mt < 4; ++mt)
      av[mt] = *(const s16x8*)(wb + ((((wid * 4 + mt) * 3 + ks) * 64 + lane) << 3));
#pragma unroll
    for (int nt = 0; nt < 2; ++nt) {
      s16x8 bv = *(const s16x8*)(xb + (nt * 16 + col) * 104 + kloc);
#pragma unroll
      for (int mt = 0; mt < 4; ++mt)
        acc[mt][nt] = __builtin_amdgcn_mfma_f32_16x16x32_bf16(av[mt], bv, acc[mt][nt], 0, 0, 0);
    }
  }
  float pbv[4][4];
#pragma unroll
  for (int mt = 0; mt < 4; ++mt)
    *(float4*)pbv[mt] = *(const float4*)(pb + (wid * 4 + mt) * 16 + quad * 4);
#pragma unroll
  for (int nt = 0; nt < 2; ++nt) {
    int t = nt * 16 + col;
#pragma unroll
    for (int mt = 0; mt < 4; ++mt) {
      int o = (wid * 4 + mt) * 16 + quad * 4;
      U4 wv;
#pragma unroll
      for (int r = 0; r < 4; ++r) wv.u[r] = f2bf(acc[mt][nt][r] + pbv[mt][r]);
      *(uint2*)&ob[t * 264 + o] = wv.v;
    }
  }
  __syncthreads();
#pragma unroll
  for (int p = 0; p < 4; ++p) {
    int idx = tid + p * 256;
    int trow = idx >> 5, cc = (idx & 31) * 8;
    *(uint4*)(hT + ((size_t)b * T_ + t0 + trow) * F_ + cc) =
        *(const uint4*)&ob[trow * 264 + cc];
  }
}

// ---------------------------------------------------------------------------
// K2: fused layer, 32-t tiles.
// ---------------------------------------------------------------------------
template <bool MASK_OUT>
__global__ __launch_bounds__(256, 4) void layer_k(
    const ushort* __restrict__ hT_in, ushort* __restrict__ hT_out,
    const float* __restrict__ mask,
    const float* __restrict__ dww, const float* __restrict__ dwb,
    const float* __restrict__ g1, const float* __restrict__ b1,
    const ushort* __restrict__ pw, const float* __restrict__ pwb,
    const float* __restrict__ g2, const float* __restrict__ b2,
    int dil) {
  __shared__ __align__(16) ushort y1b[32 * 264];
  __shared__ float stat[64];
  float* scratch = (float*)y1b;
  int tid = threadIdx.x;
  int b = blockIdx.y;
  int t0 = blockIdx.x * 32;
  const ushort* hb = hT_in + (size_t)b * T_ * F_;
  const float* mrow = mask + (size_t)b * T_;

  // ---- Phase A: conv + norm1 + gelu ----
  {
    int lane32 = tid & 31;
    int half = tid >> 5;
    int c0 = lane32 * 8;
    float dwl[24], dbv[8], g1v[8], b1v[8];
#pragma unroll
    for (int q = 0; q < 6; ++q)
      *(float4*)&dwl[q * 4] = *(const float4*)(dww + c0 * 3 + q * 4);
    *(float4*)&dbv[0] = *(const float4*)(dwb + c0);
    *(float4*)&dbv[4] = *(const float4*)(dwb + c0 + 4);
    *(float4*)&g1v[0] = *(const float4*)(g1 + c0);
    *(float4*)&g1v[4] = *(const float4*)(g1 + c0 + 4);
    *(float4*)&b1v[0] = *(const float4*)(b1 + c0);
    *(float4*)&b1v[4] = *(const float4*)(b1 + c0 + 4);
    uint4 zero4 = make_uint4(0, 0, 0, 0);
#pragma unroll 1
    for (int pass = 0; pass < 4; ++pass) {
      int t = pass * 8 + half;
      int tz = t0 + t, tm = tz - dil, tp = tz + dil;
      bool vm = (tm >= 0), vp = (tp < T_);
      float mm = vm ? mrow[tm] : 0.f;
      float mz = mrow[tz];
      float mp = vp ? mrow[tp] : 0.f;
      U8 r0, r1, r2;
      r0.v = vm ? *(const uint4*)(hb + (size_t)tm * F_ + c0) : zero4;
      r1.v = *(const uint4*)(hb + (size_t)tz * F_ + c0);
      r2.v = vp ? *(const uint4*)(hb + (size_t)tp * F_ + c0) : zero4;
      float v[8];
      float s = 0.f, q = 0.f;
#pragma unroll
      for (int i = 0; i < 8; ++i) {
        float vv = fmaf(dwl[i * 3], bf2f(r0.u[i]) * mm,
                   fmaf(dwl[i * 3 + 1], bf2f(r1.u[i]) * mz,
                   fmaf(dwl[i * 3 + 2], bf2f(r2.u[i]) * mp, dbv[i])));
        v[i] = vv;
        s += vv;
        q = fmaf(vv, vv, q);
      }
#pragma unroll
      for (int m = 1; m < 32; m <<= 1) {
        s += __shfl_xor(s, m, 32);
        q += __shfl_xor(q, m, 32);
      }
      float mean = s * (1.f / 256.f);
      float var = q * (1.f / 256.f) - mean * mean;
      float rstd = rsqrtf(var + 1e-5f);
      U8 pk;
#pragma unroll
      for (int i = 0; i < 8; ++i) {
        float u = (v[i] - mean) * rstd * g1v[i] + b1v[i];
        pk.u[i] = f2bf(gelu_f(u));
      }
      *(uint4*)&y1b[t * 264 + c0] = pk.v;
    }
  }
  __syncthreads();
  // ---- Phase B: MFMA GEMM (fragment-ordered W: coalesced A loads) ----
  int lane = tid & 63, wid = tid >> 6, col = lane & 15, quad = lane >> 4;
  f32x4 acc[4][2];
#pragma unroll
  for (int mt = 0; mt < 4; ++mt)
#pragma unroll
    for (int nt = 0; nt < 2; ++nt) acc[mt][nt] = (f32x4)(0.f);
#pragma unroll 1
  for (int ks = 0; ks < 8; ++ks) {
    int kloc = ks * 32 + quad * 8;
    s16x8 av[4];
#pragma unroll
    for (int mt = 0; mt < 4; ++mt)
      av[mt] = *(const s16x8*)(pw + ((((wid * 4 + mt) * 8 + ks) * 64 + lane) << 3));
#pragma unroll
    for (int nt = 0; nt < 2; ++nt) {
      s16x8 bv = *(const s16x8*)(y1b + (nt * 16 + col) * 264 + kloc);
#pragma unroll
      for (int mt = 0; mt < 4; ++mt)
        acc[mt][nt] = __builtin_amdgcn_mfma_f32_16x16x32_bf16(av[mt], bv, acc[mt][nt], 0, 0, 0);
    }
  }
  __syncthreads();
  // ---- Phase C: bias + per-t stats ----
  float pwbv[4][4];
#pragma unroll
  for (int mt = 0; mt < 4; ++mt)
    *(float4*)pwbv[mt] = *(const float4*)(pwb + (wid * 4 + mt) * 16 + quad * 4);
#pragma unroll
  for (int nt = 0; nt < 2; ++nt) {
    float s = 0.f, q = 0.f;
#pragma unroll
    for (int mt = 0; mt < 4; ++mt)
#pragma unroll
      for (int r = 0; r < 4; ++r) {
        float v = acc[mt][nt][r] + pwbv[mt][r];
        acc[mt][nt][r] = v;
        s += v;
        q = fmaf(v, v, q);
      }
    int pcol = (wid * 4 + quad) * 32 + nt * 16 + col;
    scratch[pcol] = s;
    scratch[512 + pcol] = q;
  }
  __syncthreads();
  if (tid < 32) {
    float s = 0.f, q = 0.f;
#pragma unroll
    for (int p = 0; p < 16; ++p) {
      s += scratch[p * 32 + tid];
      q += scratch[512 + p * 32 + tid];
    }
    float mean = s * (1.f / 256.f);
    float var = q * (1.f / 256.f) - mean * mean;
    stat[tid] = mean;
    stat[32 + tid] = rsqrtf(var + 1e-5f);
  }
  __syncthreads();
  // ---- Phase D: norm2 + gelu -> y1b ----
  {
    float g2v[4][4], b2v[4][4];
#pragma unroll
    for (int mt = 0; mt < 4; ++mt) {
      *(float4*)g2v[mt] = *(const float4*)(g2 + (wid * 4 + mt) * 16 + quad * 4);
      *(float4*)b2v[mt] = *(const float4*)(b2 + (wid * 4 + mt) * 16 + quad * 4);
    }
#pragma unroll
    for (int nt = 0; nt < 2; ++nt) {
      int t = nt * 16 + col;
      float mean = stat[t], rstd = stat[32 + t];
#pragma unroll
      for (int mt = 0; mt < 4; ++mt) {
        int o = (wid * 4 + mt) * 16 + quad * 4;
        U4 wv;
#pragma unroll
        for (int r = 0; r < 4; ++r) {
          float u = (acc[mt][nt][r] - mean) * rstd * g2v[mt][r] + b2v[mt][r];
          wv.u[r] = f2bf(gelu_f(u));
        }
        *(uint2*)&y1b[t * 264 + o] = wv.v;
      }
    }
  }
  __syncthreads();
  // ---- Phase E: coalesced residual + store ----
#pragma unroll
  for (int p = 0; p < 4; ++p) {
    int idx = tid + p * 256;
    int trow = idx >> 5, cc = (idx & 31) * 8;
    int t = t0 + trow;
    U8 yv, rv, wv;
    yv.v = *(const uint4*)&y1b[trow * 264 + cc];
    rv.v = *(const uint4*)(hb + (size_t)t * F_ + cc);
    float mval = MASK_OUT ? mrow[t] : 1.f;
#pragma unroll
    for (int i = 0; i < 8; ++i) {
      float hv = bf2f(rv.u[i]) + bf2f(yv.u[i]);
      wv.u[i] = f2bf(MASK_OUT ? hv * mval : hv);
    }
    *(uint4*)(hT_out + ((size_t)b * T_ + t) * F_ + cc) = wv.v;
  }
}

// ---------------------------------------------------------------------------
// K3: proj GEMM (fragment-ordered bf16 W) + RQ spline + logdet + x0-copy
// ---------------------------------------------------------------------------
__global__ __launch_bounds__(256, 4) void proj_spline_k(
    const ushort* __restrict__ hT,
    const float* __restrict__ x, const float* __restrict__ mask,
    const ushort* __restrict__ w_bf, const float* __restrict__ pbp,
    float* __restrict__ out, float* __restrict__ logdet) {
  __shared__ __align__(16) ushort bsm[8 * 64 * 36];
  __shared__ float red[4];
  ushort* s_lds = bsm;

  int tid = threadIdx.x;
  int t0 = blockIdx.x * 64;
  int chunk = blockIdx.y;
  int b = blockIdx.z;
  int lane = tid & 63, wid = tid >> 6, col = lane & 15, quad = lane >> 4;

#pragma unroll
  for (int p = 0; p < 8; ++p) {
    int idx = tid + p * 256;
    int row = idx >> 5;
    int u = idx & 31;
    *(uint4*)(bsm + row * 264 + u * 8) =
        *(const uint4*)(hT + ((size_t)b * T_ + t0 + row) * F_ + u * 8);
  }
  // folded x0-copy
#pragma unroll
  for (int p = 0; p < 2; ++p) {
    int idx = tid + p * 256;
    int ch = idx >> 6, t = idx & 63;
    out[((size_t)b * C_ + chunk * 8 + ch) * T_ + t0 + t] =
        x[((size_t)b * C_ + chunk * 8 + ch) * T_ + t0 + t] * mask[(size_t)b * T_ + t0 + t];
  }
  f32x4 acc[4][4];
#pragma unroll
  for (int mt = 0; mt < 4; ++mt)
#pragma unroll
    for (int nt = 0; nt < 4; ++nt) acc[mt][nt] = (f32x4)(0.f);
  const ushort* wchunk = w_bf + (size_t)chunk * 65536;
  __syncthreads();
#pragma unroll 1
  for (int ks = 0; ks < 8; ++ks) {
    int kloc = ks * 32 + quad * 8;
    s16x8 av[4];
#pragma unroll
    for (int mt = 0; mt < 4; ++mt)
      av[mt] = *(const s16x8*)(wchunk + ((((wid * 4 + mt) * 8 + ks) * 64 + lane) << 3));
#pragma unroll
    for (int nt = 0; nt < 4; ++nt) {
      s16x8 bv = *(const s16x8*)(bsm + (nt * 16 + col) * 264 + kloc);
#pragma unroll
      for (int mt = 0; mt < 4; ++mt)
        acc[mt][nt] = __builtin_amdgcn_mfma_f32_16x16x32_bf16(av[mt], bv, acc[mt][nt], 0, 0, 0);
    }
  }
  __syncthreads();
  // ---- write s-tile (permuted rows) -> [ch][t][36] ----
  {
    float mv[4];
#pragma unroll
    for (int nt = 0; nt < 4; ++nt)
      mv[nt] = mask[(size_t)b * T_ + t0 + nt * 16 + col];
#pragma unroll
    for (int mt = 0; mt < 4; ++mt) {
#pragma unroll
      for (int r = 0; r < 4; ++r) {
        int local = (wid * 4 + mt) * 16 + quad * 4 + r;
        if (local < 232) {
          int ch_i = local & 7, j = local >> 3;
          float bias = pbp[chunk * 232 + local];
#pragma unroll
          for (int nt = 0; nt < 4; ++nt)
            s_lds[ch_i * 2304 + (nt * 16 + col) * 36 + j] =
                f2bf((acc[mt][nt][r] + bias) * mv[nt]);
        }
      }
    }
  }
  __syncthreads();
  // ---- spline ----
  float lad_sum = 0.f;
  int ch_i = tid >> 5, ti = tid & 31;
  int ch = chunk * 8 + ch_i;
#pragma unroll 1
  for (int pass = 0; pass < 2; ++pass) {
    int t = ti + pass * 32;
    const ushort* sp = s_lds + ch_i * 2304 + t * 36;
    float s[29];
#pragma unroll
    for (int jj = 0; jj < 7; ++jj) {
      U4 w;
      w.v = *(const uint2*)(sp + jj * 4);
      s[jj * 4 + 0] = bf2f(w.u[0]);
      s[jj * 4 + 1] = bf2f(w.u[1]);
      s[jj * 4 + 2] = bf2f(w.u[2]);
      s[jj * 4 + 3] = bf2f(w.u[3]);
    }
    s[28] = bf2f(sp[28]);
    float xin = x[((size_t)b * C_ + HALF_ + ch) * T_ + t0 + t];
    float mval = mask[(size_t)b * T_ + t0 + t];
    const float KE = 0.09016844f;   // 0.0625 * log2(e)
    float ew[10];
    float esum = 0.f;
#pragma unroll
    for (int j = 0; j < 10; ++j) { ew[j] = __builtin_amdgcn_exp2f(s[j] * KE); esum += ew[j]; }
    float inv = __builtin_amdgcn_rcpf(esum);
    float cw[11];
    cw[0] = -5.f;
    float csum = 0.f;
#pragma unroll
    for (int j = 0; j < 9; ++j) {
      csum += fmaf(0.99f, ew[j] * inv, 0.001f);
      cw[j + 1] = fmaf(10.f, csum, -5.f);
    }
    cw[10] = 5.f;
    float eh[10];
    esum = 0.f;
#pragma unroll
    for (int j = 0; j < 10; ++j) { eh[j] = __builtin_amdgcn_exp2f(s[10 + j] * KE); esum += eh[j]; }
    inv = __builtin_amdgcn_rcpf(esum);
    float chh[11];
    chh[0] = -5.f;
    csum = 0.f;
#pragma unroll
    for (int j = 0; j < 9; ++j) {
      csum += fmaf(0.99f, eh[j] * inv, 0.001f);
      chh[j + 1] = fmaf(10.f, csum, -5.f);
    }
    chh[10] = 5.f;
    float dv[11];
    dv[0] = 1.f; dv[10] = 1.f;
#pragma unroll
    for (int j = 1; j < 10; ++j) {
      float u = s[19 + j];
      float sp_ = (u > 15.f) ? u : __logf(1.f + __expf(u));
      dv[j] = 0.001f + sp_;
    }
    float xc = fminf(fmaxf(xin, -5.f), 5.f);
    bool inside = (xin >= -5.f) && (xin <= 5.f);
    int idx = 0;
#pragma unroll
    for (int k = 1; k <= 10; ++k) idx += (xc >= cw[k]) ? 1 : 0;
    idx = idx > 9 ? 9 : idx;
    float in_cw = cw[0], in_w = cw[1] - cw[0];
    float in_ch = chh[0], in_h = chh[1] - chh[0];
    float d0 = dv[0], d1 = dv[1];
#pragma unroll
    for (int k = 1; k < 10; ++k) {
      bool sel = (idx == k);
      in_cw = sel ? cw[k] : in_cw;
      in_w = sel ? (cw[k + 1] - cw[k]) : in_w;
      in_ch = sel ? chh[k] : in_ch;
      in_h = sel ? (chh[k + 1] - chh[k]) : in_h;
      d0 = sel ? dv[k] : d0;
      d1 = sel ? dv[k + 1] : d1;
    }
    float rw = __builtin_amdgcn_rcpf(in_w);
    float theta = (xc - in_cw) * rw;
    float delta = in_h * rw;
    float omt = 1.f - theta;
    float t1m = theta * omt;
    float th2 = theta * theta;
    float denom = delta + (d0 + d1 - 2.f * delta) * t1m;
    float rd = __builtin_amdgcn_rcpf(denom);
    float num = in_h * (delta * th2 + d0 * t1m);
    float outv = in_ch + num * rd;
    float dnum = delta * delta * (d1 * th2 + 2.f * delta * t1m + d0 * omt * omt);
    float lad = __logf(dnum * rd * rd);
    float res = inside ? outv : xin;
    float ladv = inside ? lad : 0.f;
    out[((size_t)b * C_ + HALF_ + ch) * T_ + t0 + t] = res * mval;
    lad_sum += ladv * mval;
  }
#pragma unroll
  for (int off = 32; off > 0; off >>= 1)
    lad_sum += __shfl_down(lad_sum, off, 64);
  if ((tid & 63) == 0) red[tid >> 6] = lad_sum;
  __syncthreads();
  if (tid == 0)
    atomicAdd(logdet + b, red[0] + red[1] + red[2] + red[3]);
}

extern "C" void kernel_launch(void* const* d_in, const int* in_sizes, int n_in,
                              void* d_out, int out_size, void* d_ws, size_t ws_size,
                              hipStream_t stream) {
  const float* x      = (const float*)d_in[0];
  const float* mask   = (const float*)d_in[1];
  const float* pre_w  = (const float*)d_in[2];
  const float* pre_b  = (const float*)d_in[3];
  const float* dw_w   = (const float*)d_in[4];
  const float* dw_b   = (const float*)d_in[5];
  const float* pw_w   = (const float*)d_in[6];
  const float* pw_b   = (const float*)d_in[7];
  const float* g1     = (const float*)d_in[8];
  const float* b1     = (const float*)d_in[9];
  const float* g2     = (const float*)d_in[10];
  const float* b2     = (const float*)d_in[11];
  const float* proj_w = (const float*)d_in[12];
  const float* proj_b = (const float*)d_in[13];
  float* out = (float*)d_out;
  float* logdet = out + (size_t)B_ * C_ * T_;

  const size_t HSZ = (size_t)B_ * T_ * F_;
  ushort* hA    = (ushort*)d_ws;
  ushort* hB    = hA + HSZ;
  ushort* wprj  = hB + HSZ;                  // 786432 (fragment order, padded)
  ushort* wpw   = wprj + 786432;             // 196608
  ushort* wpre  = wpw + 196608;              // 24576
  float*  pbp   = (float*)(wpre + 24576);    // 2784 floats

  hipMemsetAsync(logdet, 0, B_ * sizeof(float), stream);
  wcvt_prj_k<<<dim3(786432 / 256), 256, 0, stream>>>(proj_w, proj_b, wprj, pbp);
  wcvt_pw_k<<<dim3(196608 / 256), 256, 0, stream>>>(pw_w, wpw);
  wcvt_pre_k<<<dim3(24576 / 256), 256, 0, stream>>>(pre_w, wpre);

  pre_k<<<dim3(T_ / 32, B_), 256, 0, stream>>>(x, wpre, pre_b, hA);

  layer_k<false><<<dim3(T_ / 32, B_), 256, 0, stream>>>(hA, hB, mask,
      dw_w, dw_b, g1, b1, wpw, pw_b, g2, b2, 1);
  layer_k<false><<<dim3(T_ / 32, B_), 256, 0, stream>>>(hB, hA, mask,
      dw_w + F_ * 3, dw_b + F_, g1 + F_, b1 + F_,
      wpw + 65536, pw_b + F_, g2 + F_, b2 + F_, 3);
  layer_k<true><<<dim3(T_ / 32, B_), 256, 0, stream>>>(hA, hB, mask,
      dw_w + 2 * F_ * 3, dw_b + 2 * F_, g1 + 2 * F_, b1 + 2 * F_,
      wpw + 2 * 65536, pw_b + 2 * F_, g2 + 2 * F_, b2 + 2 * F_, 9);

  proj_spline_k<<<dim3(T_ / 64, 12, B_), 256, 0, stream>>>(hB, x, mask,
      wprj, pbp, out, logdet);
}